// Round 1
// baseline (267.311 us; speedup 1.0000x reference)
//
#include <hip/hip_runtime.h>

// GCN_77584289234976 — round 1.
// Pipeline: prep(LN,e,bias) -> pool^T bf16 -> x^T/x bf16 -> S=e.e^T (fp32 VALU)
// -> row softmax -> adj bf16 -> MFMA GEMM x_agg=adj@x -> fused dual-MFMA
// (W-gen in LDS + per-node batched apply GEMM) -> out fp32.
// MFMA 16x16x32 bf16 layout contract (per cdna_hip_programming.md §3, m89/m97/m120):
//   a-frag: A[m][k], m=lane&15, k=(lane>>4)*8+j (8 contiguous k -> b128 load)
//   b-frag: B[k][n], n=lane&15, k=(lane>>4)*8+j
//   d:      D[m][n], n(col)=lane&15, m(row)=(lane>>4)*4+reg

typedef unsigned short u16;
typedef unsigned int u32;
typedef __attribute__((ext_vector_type(8))) short bf16x8;
typedef __attribute__((ext_vector_type(4))) float f32x4;

#define NN 2048
#define EE 64
#define CC 128
#define BB 32

__device__ __forceinline__ u16 f2bf(float f) {
  u32 u = __builtin_bit_cast(u32, f);
  u += 0x7fffu + ((u >> 16) & 1u);   // round-to-nearest-even
  return (u16)(u >> 16);
}

__device__ __forceinline__ f32x4 mfma16(bf16x8 a, bf16x8 b, f32x4 c) {
  return __builtin_amdgcn_mfma_f32_16x16x32_bf16(a, b, c, 0, 0, 0);
}

// ---------------- kernel 1: e = LN(node_emb + time_emb), e_bf16, bias = e@bias_pool
__global__ __launch_bounds__(64) void k_prep(
    const float* __restrict__ ne, const float* __restrict__ te,
    const float* __restrict__ lnw, const float* __restrict__ lnb,
    const float* __restrict__ bias_pool,
    float* __restrict__ e, u16* __restrict__ e_bf, float* __restrict__ bias_out) {
  int n = blockIdx.x;
  int d = threadIdx.x;
  float v = ne[n * EE + d] + te[d];
  float s = v;
#pragma unroll
  for (int off = 32; off > 0; off >>= 1) s += __shfl_xor(s, off);
  float mean = s * (1.0f / 64.0f);
  float c = v - mean;
  float q = c * c;
#pragma unroll
  for (int off = 32; off > 0; off >>= 1) q += __shfl_xor(q, off);
  float inv = rsqrtf(q * (1.0f / 64.0f) + 1e-12f);
  float ev = c * inv * lnw[d] + lnb[d];
  e[n * EE + d] = ev;
  e_bf[n * EE + d] = f2bf(ev);
  __shared__ float sh[64];
  sh[d] = ev;
  __syncthreads();
#pragma unroll
  for (int oo = 0; oo < 2; ++oo) {
    int o = oo * 64 + d;
    float acc = 0.f;
#pragma unroll 8
    for (int dd = 0; dd < 64; ++dd) acc += sh[dd] * bias_pool[dd * CC + o];
    bias_out[n * CC + o] = acc;
  }
}

// ---------------- kernel 2: pool [d][ki][o] fp32 -> pool_t [ki][o][d] bf16
__global__ __launch_bounds__(256) void k_poolt(const float* __restrict__ pool,
                                               u16* __restrict__ pool_t) {
  __shared__ float t[128 * 65];
  int ki = blockIdx.x;
  int tid = threadIdx.x;
  for (int it = 0; it < 32; ++it) {
    int idx = it * 256 + tid;
    int d = idx >> 7, o = idx & 127;
    t[o * 65 + d] = pool[d * 32768 + ki * 128 + o];
  }
  __syncthreads();
  for (int it = 0; it < 32; ++it) {
    int idx = it * 256 + tid;
    int o = idx >> 6, d = idx & 63;
    pool_t[ki * 8192 + o * 64 + d] = f2bf(t[o * 65 + d]);
  }
}

// ---------------- kernel 3: x fp32 [b][m][c] -> x_bf [b][m][c] bf16, x_t [b][c][m] bf16
__global__ __launch_bounds__(256) void k_xtrans(const float* __restrict__ x,
                                                u16* __restrict__ x_t,
                                                u16* __restrict__ x_bf) {
  __shared__ u16 t[128 * 68];
  int b = blockIdx.x >> 5;
  int m0 = (blockIdx.x & 31) * 64;
  int tid = threadIdx.x;
  for (int it = 0; it < 32; ++it) {
    int idx = it * 256 + tid;
    int m = idx >> 7, c = idx & 127;
    float v = x[(b * NN + m0 + m) * CC + c];
    u16 h = f2bf(v);
    x_bf[(b * NN + m0 + m) * CC + c] = h;
    t[c * 68 + m] = h;
  }
  __syncthreads();
  for (int it = 0; it < 32; ++it) {
    int idx = it * 256 + tid;
    int c = idx >> 6, m = idx & 63;
    x_t[(b * CC + c) * NN + m0 + m] = t[c * 68 + m];
  }
}

// ---------------- kernel 4: S = e @ e^T  (fp32, 128x128 tile, 8x8 per thread)
__global__ __launch_bounds__(256) void k_S(const float* __restrict__ e,
                                           float* __restrict__ S) {
  extern __shared__ float sm[];
  float* er = sm;              // [128][68]
  float* ec = sm + 128 * 68;   // [128][68]
  int n0 = (blockIdx.x >> 4) * 128, m0 = (blockIdx.x & 15) * 128;
  int tid = threadIdx.x;
  for (int it = 0; it < 32; ++it) {
    int idx = it * 256 + tid;
    int r = idx >> 6, d = idx & 63;
    er[r * 68 + d] = e[(n0 + r) * EE + d];
    ec[r * 68 + d] = e[(m0 + r) * EE + d];
  }
  __syncthreads();
  int tx = tid & 15, ty = tid >> 4;
  float acc[8][8] = {};
  for (int d4 = 0; d4 < 64; d4 += 4) {
    f32x4 av[8], bv[8];
#pragma unroll
    for (int i = 0; i < 8; ++i) av[i] = *(const f32x4*)&er[(ty + 16 * i) * 68 + d4];
#pragma unroll
    for (int j = 0; j < 8; ++j) bv[j] = *(const f32x4*)&ec[(tx + 16 * j) * 68 + d4];
#pragma unroll
    for (int i = 0; i < 8; ++i)
#pragma unroll
      for (int j = 0; j < 8; ++j) {
        acc[i][j] += av[i][0] * bv[j][0];
        acc[i][j] += av[i][1] * bv[j][1];
        acc[i][j] += av[i][2] * bv[j][2];
        acc[i][j] += av[i][3] * bv[j][3];
      }
  }
#pragma unroll
  for (int i = 0; i < 8; ++i)
#pragma unroll
    for (int j = 0; j < 8; ++j)
      S[(n0 + ty + 16 * i) * NN + m0 + tx + 16 * j] = acc[i][j];
}

// ---------------- kernel 5: adj = row-softmax(S) -> bf16
__global__ __launch_bounds__(256) void k_softmax(const float* __restrict__ S,
                                                 u16* __restrict__ adj) {
  int n = blockIdx.x;
  int tid = threadIdx.x;
  int lane = tid & 63, w = tid >> 6;
  __shared__ float red[8];
  const f32x4* Srow = (const f32x4*)(S + (size_t)n * NN);
  f32x4 v0 = Srow[tid];
  f32x4 v1 = Srow[256 + tid];
  float mx = v0[0];
#pragma unroll
  for (int k = 1; k < 4; ++k) mx = fmaxf(mx, v0[k]);
#pragma unroll
  for (int k = 0; k < 4; ++k) mx = fmaxf(mx, v1[k]);
#pragma unroll
  for (int off = 32; off > 0; off >>= 1) mx = fmaxf(mx, __shfl_xor(mx, off));
  if (lane == 0) red[w] = mx;
  __syncthreads();
  mx = fmaxf(fmaxf(red[0], red[1]), fmaxf(red[2], red[3]));
  float ex[8];
  float sum = 0.f;
#pragma unroll
  for (int k = 0; k < 4; ++k) { ex[k] = __expf(v0[k] - mx); sum += ex[k]; }
#pragma unroll
  for (int k = 0; k < 4; ++k) { ex[4 + k] = __expf(v1[k] - mx); sum += ex[4 + k]; }
#pragma unroll
  for (int off = 32; off > 0; off >>= 1) sum += __shfl_xor(sum, off);
  if (lane == 0) red[4 + w] = sum;
  __syncthreads();
  sum = red[4] + red[5] + red[6] + red[7];
  float rs = 1.0f / sum;
  u16* arow = adj + (size_t)n * NN;
  u32 p0 = (u32)f2bf(ex[0] * rs) | ((u32)f2bf(ex[1] * rs) << 16);
  u32 p1 = (u32)f2bf(ex[2] * rs) | ((u32)f2bf(ex[3] * rs) << 16);
  ((uint2*)arow)[tid] = make_uint2(p0, p1);
  p0 = (u32)f2bf(ex[4] * rs) | ((u32)f2bf(ex[5] * rs) << 16);
  p1 = (u32)f2bf(ex[6] * rs) | ((u32)f2bf(ex[7] * rs) << 16);
  ((uint2*)arow)[256 + tid] = make_uint2(p0, p1);
}

// ---------------- kernel 6: x_agg[b] = adj @ x[b]   (MFMA bf16, 128x128 block tile)
__global__ __launch_bounds__(256) void k_aggr(const u16* __restrict__ adj,
                                              const u16* __restrict__ x_t,
                                              u16* __restrict__ xagg) {
  __shared__ u16 As[128 * 72];  // [n-row][k]  pad 72: uniform bank-group spread
  __shared__ u16 Bs[128 * 72];  // [c][k]
  int mb = blockIdx.x & 15, b = blockIdx.x >> 4;
  int n0 = mb * 128;
  int tid = threadIdx.x;
  int lane = tid & 63, w = tid >> 6;
  int wm = w >> 1, wn = w & 1;
  int lm = lane & 15, lq = lane >> 4;
  f32x4 acc[4][4] = {};
  const u16* a_src = adj + (size_t)n0 * NN;
  const u16* b_src = x_t + (size_t)b * CC * NN;
  for (int kc = 0; kc < NN; kc += 64) {
    __syncthreads();
#pragma unroll
    for (int ii = 0; ii < 4; ++ii) {
      int idx = ii * 256 + tid;
      int row = idx >> 3, ch = idx & 7;
      *(bf16x8*)&As[row * 72 + ch * 8] = *(const bf16x8*)&a_src[(size_t)row * NN + kc + ch * 8];
      *(bf16x8*)&Bs[row * 72 + ch * 8] = *(const bf16x8*)&b_src[(size_t)row * NN + kc + ch * 8];
    }
    __syncthreads();
#pragma unroll
    for (int kk = 0; kk < 64; kk += 32) {
      bf16x8 af[4], bq[4];
#pragma unroll
      for (int i = 0; i < 4; ++i)
        af[i] = *(const bf16x8*)&As[(wm * 64 + i * 16 + lm) * 72 + kk + lq * 8];
#pragma unroll
      for (int j = 0; j < 4; ++j)
        bq[j] = *(const bf16x8*)&Bs[(wn * 64 + j * 16 + lm) * 72 + kk + lq * 8];
#pragma unroll
      for (int i = 0; i < 4; ++i)
#pragma unroll
        for (int j = 0; j < 4; ++j)
          acc[i][j] = mfma16(af[i], bq[j], acc[i][j]);
    }
  }
#pragma unroll
  for (int i = 0; i < 4; ++i) {
    int nr = n0 + wm * 64 + i * 16 + lq * 4;
#pragma unroll
    for (int j = 0; j < 4; ++j) {
      int c = wn * 64 + j * 16 + lm;
#pragma unroll
      for (int r = 0; r < 4; ++r)
        xagg[((size_t)b * NN + nr + r) * CC + c] = f2bf(acc[i][j][r]);
    }
  }
}

// ---------------- kernel 7: fused W-gen (MFMA into LDS) + per-node apply GEMM
// block: 16 nodes x 16 out-cols. phase1: W[n,ki,o]=sum_d e[n,d]*pool[d,ki,o]
// phase2: out[b,n,o] = sum_ki xg[b,n,ki]*W[n,ki,o] + bias[n,o]
__global__ __launch_bounds__(256) void k_out(const u16* __restrict__ e_bf,
                                             const u16* __restrict__ pool_t,
                                             const u16* __restrict__ x_bf,
                                             const u16* __restrict__ xagg,
                                             const float* __restrict__ bias,
                                             float* __restrict__ out) {
  extern __shared__ u16 Wl[];  // [16 nodes][16 o][264 ki]  (264: pad keeps b128 reads uniform)
  int og = blockIdx.x >> 7, ng = blockIdx.x & 127;
  int n0 = ng * 16, o0 = og * 16;
  int tid = threadIdx.x;
  int lane = tid & 63, w = tid >> 6;
  int lm = lane & 15, lq = lane >> 4;
  // phase 1: a-frag = e rows (16 nodes), b-frag = pool_t[ki][o0+lm][d-range]
  bf16x8 a0 = *(const bf16x8*)&e_bf[(n0 + lm) * EE + lq * 8];
  bf16x8 a1 = *(const bf16x8*)&e_bf[(n0 + lm) * EE + 32 + lq * 8];
#pragma unroll 4
  for (int t = 0; t < 64; ++t) {
    int ki = w * 64 + t;
    const u16* bp = pool_t + ((size_t)ki * 128 + o0 + lm) * 64 + lq * 8;
    bf16x8 b0 = *(const bf16x8*)bp;
    bf16x8 b1 = *(const bf16x8*)(bp + 32);
    f32x4 acc = {0.f, 0.f, 0.f, 0.f};
    acc = mfma16(a0, b0, acc);
    acc = mfma16(a1, b1, acc);
#pragma unroll
    for (int r = 0; r < 4; ++r) {
      int nd = lq * 4 + r;
      Wl[(nd * 16 + lm) * 264 + ki] = f2bf(acc[r]);
    }
  }
  __syncthreads();
  // phase 2: each wave handles 4 nodes; M=32 batches (2 m-tiles), K=256, N=16
#pragma unroll
  for (int nn = 0; nn < 4; ++nn) {
    int ndl = w * 4 + nn;
    int n = n0 + ndl;
    f32x4 acc0 = {0.f, 0.f, 0.f, 0.f}, acc1 = {0.f, 0.f, 0.f, 0.f};
#pragma unroll
    for (int ks = 0; ks < 8; ++ks) {
      int ki = ks * 32 + lq * 8;
      bf16x8 av0, av1;
      if (ks < 4) {
        av0 = *(const bf16x8*)&x_bf[((size_t)lm * NN + n) * CC + ki];
        av1 = *(const bf16x8*)&x_bf[(((size_t)16 + lm) * NN + n) * CC + ki];
      } else {
        av0 = *(const bf16x8*)&xagg[((size_t)lm * NN + n) * CC + ki - 128];
        av1 = *(const bf16x8*)&xagg[(((size_t)16 + lm) * NN + n) * CC + ki - 128];
      }
      bf16x8 bv = *(const bf16x8*)&Wl[(ndl * 16 + lm) * 264 + ki];
      acc0 = mfma16(av0, bv, acc0);
      acc1 = mfma16(av1, bv, acc1);
    }
    float bvv = bias[n * CC + o0 + lm];
#pragma unroll
    for (int r = 0; r < 4; ++r) {
      int br = lq * 4 + r;
      out[((size_t)br * NN + n) * CC + o0 + lm] = acc0[r] + bvv;
      out[(((size_t)16 + br) * NN + n) * CC + o0 + lm] = acc1[r] + bvv;
    }
  }
}

extern "C" void kernel_launch(void* const* d_in, const int* in_sizes, int n_in,
                              void* d_out, int out_size, void* d_ws, size_t ws_size,
                              hipStream_t stream) {
  const float* x        = (const float*)d_in[0];
  const float* node_emb = (const float*)d_in[1];
  const float* time_emb = (const float*)d_in[2];
  const float* pool     = (const float*)d_in[3];
  const float* bias_pl  = (const float*)d_in[4];
  const float* ln_w     = (const float*)d_in[5];
  const float* ln_b     = (const float*)d_in[6];
  float* out = (float*)d_out;

  char* p = (char*)d_ws;
  auto alloc = [&](size_t bytes) {
    char* r = p;
    p += (bytes + 255) & ~(size_t)255;
    return r;
  };
  float* e      = (float*)alloc((size_t)NN * EE * 4);
  u16*   e_bf   = (u16*)  alloc((size_t)NN * EE * 2);
  float* biasb  = (float*)alloc((size_t)NN * CC * 4);
  u16*   adj    = (u16*)  alloc((size_t)NN * NN * 2);
  u16*   x_t    = (u16*)  alloc((size_t)BB * CC * NN * 2);
  u16*   x_bf   = (u16*)  alloc((size_t)BB * NN * CC * 2);
  u16*   pool_t = (u16*)  alloc((size_t)256 * 128 * 64 * 2);
  char*  Sx     = alloc((size_t)NN * NN * 4);  // S fp32; later aliased by x_agg bf16
  float* S      = (float*)Sx;
  u16*   xagg   = (u16*)Sx;  // safe: S fully consumed by k_softmax before k_aggr writes

  if (ws_size < (size_t)(p - (char*)d_ws)) return;  // insufficient scratch -> fail loudly

  // >64KB dynamic LDS kernels need the opt-in attribute (host-side, capture-safe)
  (void)hipFuncSetAttribute((const void*)k_S, hipFuncAttributeMaxDynamicSharedMemorySize,
                            2 * 128 * 68 * 4);
  (void)hipFuncSetAttribute((const void*)k_out, hipFuncAttributeMaxDynamicSharedMemorySize,
                            16 * 16 * 264 * 2);

  k_prep<<<NN, 64, 0, stream>>>(node_emb, time_emb, ln_w, ln_b, bias_pl, e, e_bf, biasb);
  k_poolt<<<256, 256, 0, stream>>>(pool, pool_t);
  k_xtrans<<<BB * 32, 256, 0, stream>>>(x, x_t, x_bf);
  k_S<<<256, 256, 2 * 128 * 68 * 4, stream>>>(e, S);
  k_softmax<<<NN, 256, 0, stream>>>(S, adj);
  k_aggr<<<16 * BB, 256, 0, stream>>>(adj, x_t, xagg);
  k_out<<<8 * 128, 256, 16 * 16 * 264 * 2, stream>>>(e_bf, pool_t, x_bf, xagg, biasb, out);
}

// Round 2
// 253.780 us; speedup vs baseline: 1.0533x; 1.0533x over previous
//
#include <hip/hip_runtime.h>

// GCN_77584289234976 — round 2.
// R1: 267us, k_out=104us @ 10.8% occupancy (132KB LDS -> 1 blk/CU) + scalar u16
// LDS writes. R2: k_out rewritten: ki-chunked 38KB LDS (2 blk/CU, 16 waves),
// gen-GEMM transposed so C-layout rows = consecutive ki -> b64 LDS writes,
// pool re-laid as pool_r[o][ki][d] for coalesced a-frag streams.
// MFMA 16x16x32 bf16 layout contract (m89/m97/m120):
//   a-frag: A[m][k], m=lane&15, k=(lane>>4)*8+j
//   b-frag: B[k][n], n=lane&15, k=(lane>>4)*8+j
//   d:      D[m][n], n(col)=lane&15, m(row)=(lane>>4)*4+reg

typedef unsigned short u16;
typedef unsigned int u32;
typedef __attribute__((ext_vector_type(8))) short bf16x8;
typedef __attribute__((ext_vector_type(4))) float f32x4;

#define NN 2048
#define EE 64
#define CC 128
#define BB 32

__device__ __forceinline__ u16 f2bf(float f) {
  u32 u = __builtin_bit_cast(u32, f);
  u += 0x7fffu + ((u >> 16) & 1u);   // round-to-nearest-even
  return (u16)(u >> 16);
}

__device__ __forceinline__ f32x4 mfma16(bf16x8 a, bf16x8 b, f32x4 c) {
  return __builtin_amdgcn_mfma_f32_16x16x32_bf16(a, b, c, 0, 0, 0);
}

// ---------------- kernel 1: e = LN(node_emb + time_emb), e_bf16, bias = e@bias_pool
__global__ __launch_bounds__(64) void k_prep(
    const float* __restrict__ ne, const float* __restrict__ te,
    const float* __restrict__ lnw, const float* __restrict__ lnb,
    const float* __restrict__ bias_pool,
    float* __restrict__ e, u16* __restrict__ e_bf, float* __restrict__ bias_out) {
  int n = blockIdx.x;
  int d = threadIdx.x;
  float v = ne[n * EE + d] + te[d];
  float s = v;
#pragma unroll
  for (int off = 32; off > 0; off >>= 1) s += __shfl_xor(s, off);
  float mean = s * (1.0f / 64.0f);
  float c = v - mean;
  float q = c * c;
#pragma unroll
  for (int off = 32; off > 0; off >>= 1) q += __shfl_xor(q, off);
  float inv = rsqrtf(q * (1.0f / 64.0f) + 1e-12f);
  float ev = c * inv * lnw[d] + lnb[d];
  e[n * EE + d] = ev;
  e_bf[n * EE + d] = f2bf(ev);
  __shared__ float sh[64];
  sh[d] = ev;
  __syncthreads();
#pragma unroll
  for (int oo = 0; oo < 2; ++oo) {
    int o = oo * 64 + d;
    float acc = 0.f;
#pragma unroll 8
    for (int dd = 0; dd < 64; ++dd) acc += sh[dd] * bias_pool[dd * CC + o];
    bias_out[n * CC + o] = acc;
  }
}

// ---------------- kernel 2: pool [d][ki][o] fp32 -> pool_r [o][ki][d] bf16
__global__ __launch_bounds__(256) void k_poolt(const float* __restrict__ pool,
                                               u16* __restrict__ pool_r) {
  __shared__ float t[128 * 65];
  int ki = blockIdx.x;
  int tid = threadIdx.x;
  for (int it = 0; it < 32; ++it) {
    int idx = it * 256 + tid;
    int d = idx >> 7, o = idx & 127;
    t[o * 65 + d] = pool[d * 32768 + ki * 128 + o];
  }
  __syncthreads();
  for (int it = 0; it < 32; ++it) {
    int idx = it * 256 + tid;
    int o = idx >> 6, d = idx & 63;
    pool_r[((size_t)o * 256 + ki) * 64 + d] = f2bf(t[o * 65 + d]);
  }
}

// ---------------- kernel 3: x fp32 [b][m][c] -> x_bf [b][m][c] bf16, x_t [b][c][m] bf16
__global__ __launch_bounds__(256) void k_xtrans(const float* __restrict__ x,
                                                u16* __restrict__ x_t,
                                                u16* __restrict__ x_bf) {
  __shared__ u16 t[128 * 68];
  int b = blockIdx.x >> 5;
  int m0 = (blockIdx.x & 31) * 64;
  int tid = threadIdx.x;
  for (int it = 0; it < 32; ++it) {
    int idx = it * 256 + tid;
    int m = idx >> 7, c = idx & 127;
    float v = x[(b * NN + m0 + m) * CC + c];
    u16 h = f2bf(v);
    x_bf[(b * NN + m0 + m) * CC + c] = h;
    t[c * 68 + m] = h;
  }
  __syncthreads();
  for (int it = 0; it < 32; ++it) {
    int idx = it * 256 + tid;
    int c = idx >> 6, m = idx & 63;
    x_t[(b * CC + c) * NN + m0 + m] = t[c * 68 + m];
  }
}

// ---------------- kernel 4: S = e @ e^T  (fp32, 128x128 tile, 8x8 per thread)
__global__ __launch_bounds__(256) void k_S(const float* __restrict__ e,
                                           float* __restrict__ S) {
  extern __shared__ float sm[];
  float* er = sm;              // [128][68]
  float* ec = sm + 128 * 68;   // [128][68]
  int n0 = (blockIdx.x >> 4) * 128, m0 = (blockIdx.x & 15) * 128;
  int tid = threadIdx.x;
  for (int it = 0; it < 32; ++it) {
    int idx = it * 256 + tid;
    int r = idx >> 6, d = idx & 63;
    er[r * 68 + d] = e[(n0 + r) * EE + d];
    ec[r * 68 + d] = e[(m0 + r) * EE + d];
  }
  __syncthreads();
  int tx = tid & 15, ty = tid >> 4;
  float acc[8][8] = {};
  for (int d4 = 0; d4 < 64; d4 += 4) {
    f32x4 av[8], bv[8];
#pragma unroll
    for (int i = 0; i < 8; ++i) av[i] = *(const f32x4*)&er[(ty + 16 * i) * 68 + d4];
#pragma unroll
    for (int j = 0; j < 8; ++j) bv[j] = *(const f32x4*)&ec[(tx + 16 * j) * 68 + d4];
#pragma unroll
    for (int i = 0; i < 8; ++i)
#pragma unroll
      for (int j = 0; j < 8; ++j) {
        acc[i][j] += av[i][0] * bv[j][0];
        acc[i][j] += av[i][1] * bv[j][1];
        acc[i][j] += av[i][2] * bv[j][2];
        acc[i][j] += av[i][3] * bv[j][3];
      }
  }
#pragma unroll
  for (int i = 0; i < 8; ++i)
#pragma unroll
    for (int j = 0; j < 8; ++j)
      S[(n0 + ty + 16 * i) * NN + m0 + tx + 16 * j] = acc[i][j];
}

// ---------------- kernel 5: adj = row-softmax(S) -> bf16
__global__ __launch_bounds__(256) void k_softmax(const float* __restrict__ S,
                                                 u16* __restrict__ adj) {
  int n = blockIdx.x;
  int tid = threadIdx.x;
  int lane = tid & 63, w = tid >> 6;
  __shared__ float red[8];
  const f32x4* Srow = (const f32x4*)(S + (size_t)n * NN);
  f32x4 v0 = Srow[tid];
  f32x4 v1 = Srow[256 + tid];
  float mx = v0[0];
#pragma unroll
  for (int k = 1; k < 4; ++k) mx = fmaxf(mx, v0[k]);
#pragma unroll
  for (int k = 0; k < 4; ++k) mx = fmaxf(mx, v1[k]);
#pragma unroll
  for (int off = 32; off > 0; off >>= 1) mx = fmaxf(mx, __shfl_xor(mx, off));
  if (lane == 0) red[w] = mx;
  __syncthreads();
  mx = fmaxf(fmaxf(red[0], red[1]), fmaxf(red[2], red[3]));
  float ex[8];
  float sum = 0.f;
#pragma unroll
  for (int k = 0; k < 4; ++k) { ex[k] = __expf(v0[k] - mx); sum += ex[k]; }
#pragma unroll
  for (int k = 0; k < 4; ++k) { ex[4 + k] = __expf(v1[k] - mx); sum += ex[4 + k]; }
#pragma unroll
  for (int off = 32; off > 0; off >>= 1) sum += __shfl_xor(sum, off);
  if (lane == 0) red[4 + w] = sum;
  __syncthreads();
  sum = red[4] + red[5] + red[6] + red[7];
  float rs = 1.0f / sum;
  u16* arow = adj + (size_t)n * NN;
  u32 p0 = (u32)f2bf(ex[0] * rs) | ((u32)f2bf(ex[1] * rs) << 16);
  u32 p1 = (u32)f2bf(ex[2] * rs) | ((u32)f2bf(ex[3] * rs) << 16);
  ((uint2*)arow)[tid] = make_uint2(p0, p1);
  p0 = (u32)f2bf(ex[4] * rs) | ((u32)f2bf(ex[5] * rs) << 16);
  p1 = (u32)f2bf(ex[6] * rs) | ((u32)f2bf(ex[7] * rs) << 16);
  ((uint2*)arow)[256 + tid] = make_uint2(p0, p1);
}

// ---------------- kernel 6: x_agg[b] = adj @ x[b]   (MFMA bf16, 128x128 block tile)
__global__ __launch_bounds__(256) void k_aggr(const u16* __restrict__ adj,
                                              const u16* __restrict__ x_t,
                                              u16* __restrict__ xagg) {
  __shared__ u16 As[128 * 72];  // [n-row][k]
  __shared__ u16 Bs[128 * 72];  // [c][k]
  int mb = blockIdx.x & 15, b = blockIdx.x >> 4;
  int n0 = mb * 128;
  int tid = threadIdx.x;
  int lane = tid & 63, w = tid >> 6;
  int wm = w >> 1, wn = w & 1;
  int lm = lane & 15, lq = lane >> 4;
  f32x4 acc[4][4] = {};
  const u16* a_src = adj + (size_t)n0 * NN;
  const u16* b_src = x_t + (size_t)b * CC * NN;
  for (int kc = 0; kc < NN; kc += 64) {
    __syncthreads();
#pragma unroll
    for (int ii = 0; ii < 4; ++ii) {
      int idx = ii * 256 + tid;
      int row = idx >> 3, ch = idx & 7;
      *(bf16x8*)&As[row * 72 + ch * 8] = *(const bf16x8*)&a_src[(size_t)row * NN + kc + ch * 8];
      *(bf16x8*)&Bs[row * 72 + ch * 8] = *(const bf16x8*)&b_src[(size_t)row * NN + kc + ch * 8];
    }
    __syncthreads();
#pragma unroll
    for (int kk = 0; kk < 64; kk += 32) {
      bf16x8 af[4], bq[4];
#pragma unroll
      for (int i = 0; i < 4; ++i)
        af[i] = *(const bf16x8*)&As[(wm * 64 + i * 16 + lm) * 72 + kk + lq * 8];
#pragma unroll
      for (int j = 0; j < 4; ++j)
        bq[j] = *(const bf16x8*)&Bs[(wn * 64 + j * 16 + lm) * 72 + kk + lq * 8];
#pragma unroll
      for (int i = 0; i < 4; ++i)
#pragma unroll
        for (int j = 0; j < 4; ++j)
          acc[i][j] = mfma16(af[i], bq[j], acc[i][j]);
    }
  }
#pragma unroll
  for (int i = 0; i < 4; ++i) {
    int nr = n0 + wm * 64 + i * 16 + lq * 4;
#pragma unroll
    for (int j = 0; j < 4; ++j) {
      int c = wn * 64 + j * 16 + lm;
#pragma unroll
      for (int r = 0; r < 4; ++r)
        xagg[((size_t)b * NN + nr + r) * CC + c] = f2bf(acc[i][j][r]);
    }
  }
}

// ---------------- kernel 7 (v2): fused W-gen + per-node apply, ki-chunked
// block: 16 nodes x 32 o, 512 threads (8 waves), 8 chunks of 32 ki.
// gen (per chunk): D[m=ki16][n=node16] = pool_r[ki][d] @ e^T[d][node]
//   -> C-layout rows = 4 consecutive ki -> one b64 LDS write per lane per tile.
// apply: out[b][o] += xg[b][ki] @ W[ki][o], W read from LDS as b-frags.
// LDS Wl[node][o][ki32]: o-stride 36, node-stride 1192 (16B aligned, banks spread).
#define WL_OS 36
#define WL_NS 1192
__global__ __launch_bounds__(512, 4) void k_out(const u16* __restrict__ e_bf,
                                                const u16* __restrict__ pool_r,
                                                const u16* __restrict__ x_bf,
                                                const u16* __restrict__ xagg,
                                                const float* __restrict__ bias,
                                                float* __restrict__ out) {
  __shared__ u16 Wl[16 * WL_NS];  // 38,144 B -> 2 blocks/CU, 16 waves/CU
  int ng = blockIdx.x & 127, og = blockIdx.x >> 7;
  int n0 = ng * 16, o0 = og * 32;
  int tid = threadIdx.x;
  int lane = tid & 63, w = tid >> 6;   // w in 0..7
  int lm = lane & 15, lq = lane >> 4;
  // e b-frags: B[k=d][n=node], node=lm; loaded once, reused all chunks
  bf16x8 e0 = *(const bf16x8*)&e_bf[(n0 + lm) * EE + lq * 8];
  bf16x8 e1 = *(const bf16x8*)&e_bf[(n0 + lm) * EE + 32 + lq * 8];
  f32x4 acc[2][2][2] = {};   // [node][mt(batch half)][nt(o half)]
  for (int c = 0; c < 8; ++c) {
    // ---- gen: W[node][o][ki] for this 32-ki chunk; wave w covers o = w*4..w*4+3
#pragma unroll
    for (int oi = 0; oi < 4; ++oi) {
      int o = w * 4 + oi;
#pragma unroll
      for (int kh = 0; kh < 2; ++kh) {
        const u16* ap = pool_r + ((size_t)(o0 + o) * 256 + c * 32 + kh * 16 + lm) * 64 + lq * 8;
        bf16x8 p0 = *(const bf16x8*)ap;
        bf16x8 p1 = *(const bf16x8*)(ap + 32);
        f32x4 g = {0.f, 0.f, 0.f, 0.f};
        g = mfma16(p0, e0, g);
        g = mfma16(p1, e1, g);
        ushort4 h;
        h.x = f2bf(g[0]); h.y = f2bf(g[1]); h.z = f2bf(g[2]); h.w = f2bf(g[3]);
        // lane holds node=lm (col), ki = kh*16 + lq*4 + r (rows) -> b64 write
        *(ushort4*)&Wl[lm * WL_NS + o * WL_OS + kh * 16 + lq * 4] = h;
      }
    }
    __syncthreads();
    // ---- apply: wave w owns nodes w*2, w*2+1; M=32 batch (2 tiles), N=32 o (2 tiles), K=32
#pragma unroll
    for (int nn = 0; nn < 2; ++nn) {
      int ndl = w * 2 + nn;
      int n = n0 + ndl;
      const u16* xs = (c < 4) ? x_bf : xagg;
      int ck = (c < 4) ? c * 32 : c * 32 - 128;
      bf16x8 a0 = *(const bf16x8*)&xs[((size_t)lm * NN + n) * CC + ck + lq * 8];
      bf16x8 a1 = *(const bf16x8*)&xs[(((size_t)16 + lm) * NN + n) * CC + ck + lq * 8];
#pragma unroll
      for (int nt = 0; nt < 2; ++nt) {
        bf16x8 bv = *(const bf16x8*)&Wl[ndl * WL_NS + (nt * 16 + lm) * WL_OS + lq * 8];
        acc[nn][0][nt] = mfma16(a0, bv, acc[nn][0][nt]);
        acc[nn][1][nt] = mfma16(a1, bv, acc[nn][1][nt]);
      }
    }
    __syncthreads();
  }
  // ---- epilogue: D col=lm -> o, rows lq*4+r -> batch within m-tile
#pragma unroll
  for (int nn = 0; nn < 2; ++nn) {
    int n = n0 + w * 2 + nn;
#pragma unroll
    for (int nt = 0; nt < 2; ++nt) {
      int oc = o0 + nt * 16 + lm;
      float bv = bias[n * CC + oc];
#pragma unroll
      for (int mt = 0; mt < 2; ++mt) {
#pragma unroll
        for (int r = 0; r < 4; ++r) {
          int b = mt * 16 + lq * 4 + r;
          out[((size_t)b * NN + n) * CC + oc] = acc[nn][mt][nt][r] + bv;
        }
      }
    }
  }
}

extern "C" void kernel_launch(void* const* d_in, const int* in_sizes, int n_in,
                              void* d_out, int out_size, void* d_ws, size_t ws_size,
                              hipStream_t stream) {
  const float* x        = (const float*)d_in[0];
  const float* node_emb = (const float*)d_in[1];
  const float* time_emb = (const float*)d_in[2];
  const float* pool     = (const float*)d_in[3];
  const float* bias_pl  = (const float*)d_in[4];
  const float* ln_w     = (const float*)d_in[5];
  const float* ln_b     = (const float*)d_in[6];
  float* out = (float*)d_out;

  char* p = (char*)d_ws;
  auto alloc = [&](size_t bytes) {
    char* r = p;
    p += (bytes + 255) & ~(size_t)255;
    return r;
  };
  float* e      = (float*)alloc((size_t)NN * EE * 4);
  u16*   e_bf   = (u16*)  alloc((size_t)NN * EE * 2);
  float* biasb  = (float*)alloc((size_t)NN * CC * 4);
  u16*   adj    = (u16*)  alloc((size_t)NN * NN * 2);
  u16*   x_t    = (u16*)  alloc((size_t)BB * CC * NN * 2);
  u16*   x_bf   = (u16*)  alloc((size_t)BB * NN * CC * 2);
  u16*   pool_r = (u16*)  alloc((size_t)128 * 256 * 64 * 2);
  char*  Sx     = alloc((size_t)NN * NN * 4);  // S fp32; later aliased by x_agg bf16
  float* S      = (float*)Sx;
  u16*   xagg   = (u16*)Sx;  // safe: S fully consumed by k_softmax before k_aggr writes

  if (ws_size < (size_t)(p - (char*)d_ws)) return;

  (void)hipFuncSetAttribute((const void*)k_S, hipFuncAttributeMaxDynamicSharedMemorySize,
                            2 * 128 * 68 * 4);

  k_prep<<<NN, 64, 0, stream>>>(node_emb, time_emb, ln_w, ln_b, bias_pl, e, e_bf, biasb);
  k_poolt<<<256, 256, 0, stream>>>(pool, pool_r);
  k_xtrans<<<BB * 32, 256, 0, stream>>>(x, x_t, x_bf);
  k_S<<<256, 256, 2 * 128 * 68 * 4, stream>>>(e, S);
  k_softmax<<<NN, 256, 0, stream>>>(S, adj);
  k_aggr<<<16 * BB, 256, 0, stream>>>(adj, x_t, xagg);
  k_out<<<512, 512, 0, stream>>>(e_bf, pool_r, x_bf, xagg, biasb, out);
}